// Round 3
// baseline (150.731 us; speedup 1.0000x reference)
//
#include <hip/hip_runtime.h>
#include <math.h>

// DSoftKI: B=16384, M=512, D=8
//   diff = x[:,None,:]/T - z            [B,M,D]
//   dist = ||diff||                     [B,M]
//   W    = softmax(-dist, axis=-1)      [B,M]
//   dd   = diff/(dist+1e-6)/T           [B,M,D]
//   mean = einsum('bm,bmd->bd', W, dd)  [B,D]
//   deriv= -W*(dd - mean)               [B,M,D]
//   out  = concat([W, deriv.transpose(0,2,1).reshape(B*D, M)])  [B*(D+1), M]
//
// R3: store-width fix. R2 = 56.2us vs 44us write roofline (302MB @ 6.9TB/s
// fill-rate). 72 dword stores/wave (4B/lane) -> 18 dwordx4 stores/wave
// (16B/lane sweet spot). Lane now owns 8 CONSECUTIVE m's (m=lane*8+j);
// LDS rows stored at swizzled slot ((m&7)*64 + m>>3) so the read bank
// pattern is identical to R2's (lane*20 mod 32 covers all banks per 8
// lanes). Wave reductions unchanged (ownership-agnostic).

#define B_N 16384
#define M_N 512
#define D_N 8
#define ROWF 20  // floats per LDS row: 8 z + 8 invT + 4 pad (80B stride)
#define LOG2E 1.4426950408889634f

typedef float f32x4 __attribute__((ext_vector_type(4)));

__global__ __launch_bounds__(512) void dsoftki_kernel(
    const float* __restrict__ x,
    const float* __restrict__ z,
    const float* __restrict__ T,
    float* __restrict__ out)
{
    __shared__ float zt[M_N * ROWF];  // 40 KB

    const int tid = threadIdx.x;

    // ---- stage z and 1/T into LDS at swizzled slot (once per block) ----
    {
        const int m = tid;  // M_N == 512 == blockDim.x
        const int slot = ((m & 7) << 6) + (m >> 3);
        const float4* zp = (const float4*)(z + m * 8);
        float4 z0 = zp[0], z1 = zp[1];
        const float4* tp = (const float4*)(T + m * 8);
        float4 t0 = tp[0], t1 = tp[1];
        float* row = zt + slot * ROWF;
        ((float4*)row)[0] = z0;
        ((float4*)row)[1] = z1;
        row[8]  = __builtin_amdgcn_rcpf(t0.x);
        row[9]  = __builtin_amdgcn_rcpf(t0.y);
        row[10] = __builtin_amdgcn_rcpf(t0.z);
        row[11] = __builtin_amdgcn_rcpf(t0.w);
        row[12] = __builtin_amdgcn_rcpf(t1.x);
        row[13] = __builtin_amdgcn_rcpf(t1.y);
        row[14] = __builtin_amdgcn_rcpf(t1.z);
        row[15] = __builtin_amdgcn_rcpf(t1.w);
    }
    __syncthreads();

    const int wave = tid >> 6;
    const int lane = tid & 63;
    const int b = blockIdx.x * 8 + wave;

    // ---- x[b] (broadcast load, L1-served) ----
    float xb[8];
    {
        const float4* xp = (const float4*)(x + (size_t)b * 8);
        float4 x0 = xp[0], x1 = xp[1];
        xb[0] = x0.x; xb[1] = x0.y; xb[2] = x0.z; xb[3] = x0.w;
        xb[4] = x1.x; xb[5] = x1.y; xb[6] = x1.z; xb[7] = x1.w;
    }

    // ---- pass: dist + dd (kept in regs), unnormalized weights e[j] ----
    // lane owns m = lane*8 + j, staged at slot j*64 + lane
    float dd[8][8];
    float e[8];

    #pragma unroll
    for (int j = 0; j < 8; ++j) {
        const float* row = zt + ((j << 6) + lane) * ROWF;
        float4 zz0 = ((const float4*)row)[0];
        float4 zz1 = ((const float4*)row)[1];
        float4 it0 = ((const float4*)row)[2];
        float4 it1 = ((const float4*)row)[3];
        float zr[8] = {zz0.x, zz0.y, zz0.z, zz0.w, zz1.x, zz1.y, zz1.z, zz1.w};
        float ir[8] = {it0.x, it0.y, it0.z, it0.w, it1.x, it1.y, it1.z, it1.w};

        float diff[8];
        float ss = 0.f;
        #pragma unroll
        for (int d = 0; d < 8; ++d) {
            float df = xb[d] * ir[d] - zr[d];   // x/T - z
            diff[d] = df * ir[d];               // pre-scale by 1/T for dd
            ss = fmaf(df, df, ss);
        }
        float dist = __builtin_amdgcn_sqrtf(ss);
        // exp(-dist), dist in [0, ~25]: no overflow/underflow; max-sub skipped.
        e[j] = __builtin_amdgcn_exp2f(-dist * LOG2E);
        float inv = __builtin_amdgcn_rcpf(dist + 1e-6f);
        #pragma unroll
        for (int d = 0; d < 8; ++d) dd[j][d] = diff[d] * inv;
    }

    // ---- 9 independent wave reductions: se = sum e, acc[d] = sum e*dd ----
    float se = e[0] + e[1] + e[2] + e[3] + e[4] + e[5] + e[6] + e[7];
    float acc[8];
    #pragma unroll
    for (int d = 0; d < 8; ++d) {
        float a = 0.f;
        #pragma unroll
        for (int j = 0; j < 8; ++j) a = fmaf(e[j], dd[j][d], a);
        acc[d] = a;
    }
    #pragma unroll
    for (int o = 32; o > 0; o >>= 1) {
        se += __shfl_xor(se, o, 64);
        #pragma unroll
        for (int d = 0; d < 8; ++d) acc[d] += __shfl_xor(acc[d], o, 64);
    }
    const float sinv = __builtin_amdgcn_rcpf(se);

    // ---- W stores first (start HBM early): lane's 8 consecutive floats ----
    float w[8];
    #pragma unroll
    for (int j = 0; j < 8; ++j) w[j] = e[j] * sinv;
    {
        float* p = out + (size_t)b * M_N + lane * 8;
        f32x4 w0 = {w[0], w[1], w[2], w[3]};
        f32x4 w1 = {w[4], w[5], w[6], w[7]};
        __builtin_nontemporal_store(w0, (f32x4*)p);
        __builtin_nontemporal_store(w1, (f32x4*)(p + 4));
    }

    // ---- deriv = w*(mean - dd), mean[d] = acc[d]*sinv ----
    float meanv[8];
    #pragma unroll
    for (int d = 0; d < 8; ++d) meanv[d] = acc[d] * sinv;

    float* outD = out + (size_t)B_N * M_N + (size_t)b * (D_N * M_N) + lane * 8;
    #pragma unroll
    for (int d = 0; d < 8; ++d) {
        float v[8];
        #pragma unroll
        for (int j = 0; j < 8; ++j) v[j] = w[j] * (meanv[d] - dd[j][d]);
        f32x4 v0 = {v[0], v[1], v[2], v[3]};
        f32x4 v1 = {v[4], v[5], v[6], v[7]};
        float* p = outD + d * M_N;
        __builtin_nontemporal_store(v0, (f32x4*)p);
        __builtin_nontemporal_store(v1, (f32x4*)(p + 4));
    }
}

extern "C" void kernel_launch(void* const* d_in, const int* in_sizes, int n_in,
                              void* d_out, int out_size, void* d_ws, size_t ws_size,
                              hipStream_t stream) {
    const float* x = (const float*)d_in[0];
    const float* z = (const float*)d_in[1];
    const float* T = (const float*)d_in[2];
    float* out = (float*)d_out;

    dim3 grid(B_N / 8);   // 8 waves per block, 1 batch row per wave
    dim3 block(512);
    dsoftki_kernel<<<grid, block, 0, stream>>>(x, z, T, out);
}

// Round 4
// 58.788 us; speedup vs baseline: 2.5640x; 2.5640x over previous
//
#include <hip/hip_runtime.h>
#include <math.h>

// DSoftKI: B=16384, M=512, D=8
//   diff = x[:,None,:]/T - z            [B,M,D]
//   dist = ||diff||                     [B,M]
//   W    = softmax(-dist, axis=-1)      [B,M]
//   dd   = diff/(dist+1e-6)/T           [B,M,D]
//   mean = einsum('bm,bmd->bd', W, dd)  [B,D]
//   deriv= -W*(dd - mean)               [B,M,D]
//   out  = concat([W, deriv.transpose(0,2,1).reshape(B*D, M)])  [B*(D+1), M]
//
// R4: contiguous-per-instruction wide stores. R3's lane*32B blocked layout
// made every dwordx4 instruction touch 64 disjoint 16B segments (partial
// 64B lines -> write amplification, 150us). Fix: lane L owns
// m = c*256 + L*4 + j (c in {0,1}, j in {0..3}) so each of the 18 dwordx4
// stores covers a contiguous 1KB span (fill-kernel pattern, 6.9 TB/s).
// LDS slot = j*128 + c*64 + L keeps the read address stream identical to
// R2's conflict-free lane*20 pattern. Staging iterates by slot (z/T gather
// is 16KB, L2-resident).

#define B_N 16384
#define M_N 512
#define D_N 8
#define ROWF 20  // floats per LDS row: 8 z + 8 invT + 4 pad (80B stride)
#define LOG2E 1.4426950408889634f

typedef float f32x4 __attribute__((ext_vector_type(4)));

__global__ __launch_bounds__(512) void dsoftki_kernel(
    const float* __restrict__ x,
    const float* __restrict__ z,
    const float* __restrict__ T,
    float* __restrict__ out)
{
    __shared__ float zt[M_N * ROWF];  // 40 KB

    const int tid = threadIdx.x;

    // ---- stage z and 1/T into LDS, iterating by slot (once per block) ----
    // slot s (= tid) holds m = c*256 + q*4 + j where j=s>>7, c=(s>>6)&1, q=s&63
    {
        const int s = tid;  // M_N == 512 == blockDim.x
        const int j = s >> 7;
        const int c = (s >> 6) & 1;
        const int q = s & 63;
        const int m = c * 256 + q * 4 + j;
        const float4* zp = (const float4*)(z + m * 8);
        float4 z0 = zp[0], z1 = zp[1];
        const float4* tp = (const float4*)(T + m * 8);
        float4 t0 = tp[0], t1 = tp[1];
        float* row = zt + s * ROWF;
        ((float4*)row)[0] = z0;
        ((float4*)row)[1] = z1;
        row[8]  = __builtin_amdgcn_rcpf(t0.x);
        row[9]  = __builtin_amdgcn_rcpf(t0.y);
        row[10] = __builtin_amdgcn_rcpf(t0.z);
        row[11] = __builtin_amdgcn_rcpf(t0.w);
        row[12] = __builtin_amdgcn_rcpf(t1.x);
        row[13] = __builtin_amdgcn_rcpf(t1.y);
        row[14] = __builtin_amdgcn_rcpf(t1.z);
        row[15] = __builtin_amdgcn_rcpf(t1.w);
    }
    __syncthreads();

    const int wave = tid >> 6;
    const int lane = tid & 63;
    const int b = blockIdx.x * 8 + wave;

    // ---- x[b] (broadcast load, L1-served) ----
    float xb[8];
    {
        const float4* xp = (const float4*)(x + (size_t)b * 8);
        float4 x0 = xp[0], x1 = xp[1];
        xb[0] = x0.x; xb[1] = x0.y; xb[2] = x0.z; xb[3] = x0.w;
        xb[4] = x1.x; xb[5] = x1.y; xb[6] = x1.z; xb[7] = x1.w;
    }

    // ---- pass: dist + dd (kept in regs), unnormalized weights e ----
    // lane owns m = c*256 + lane*4 + j, staged at slot j*128 + c*64 + lane
    float dd[2][4][8];
    float e[2][4];

    #pragma unroll
    for (int c = 0; c < 2; ++c) {
        #pragma unroll
        for (int j = 0; j < 4; ++j) {
            const float* row = zt + (j * 128 + c * 64 + lane) * ROWF;
            float4 zz0 = ((const float4*)row)[0];
            float4 zz1 = ((const float4*)row)[1];
            float4 it0 = ((const float4*)row)[2];
            float4 it1 = ((const float4*)row)[3];
            float zr[8] = {zz0.x, zz0.y, zz0.z, zz0.w, zz1.x, zz1.y, zz1.z, zz1.w};
            float ir[8] = {it0.x, it0.y, it0.z, it0.w, it1.x, it1.y, it1.z, it1.w};

            float diff[8];
            float ss = 0.f;
            #pragma unroll
            for (int d = 0; d < 8; ++d) {
                float df = xb[d] * ir[d] - zr[d];   // x/T - z
                diff[d] = df * ir[d];               // pre-scale by 1/T for dd
                ss = fmaf(df, df, ss);
            }
            float dist = __builtin_amdgcn_sqrtf(ss);
            // exp(-dist), dist in [0, ~25]: no overflow/underflow; max-sub skipped.
            e[c][j] = __builtin_amdgcn_exp2f(-dist * LOG2E);
            float inv = __builtin_amdgcn_rcpf(dist + 1e-6f);
            #pragma unroll
            for (int d = 0; d < 8; ++d) dd[c][j][d] = diff[d] * inv;
        }
    }

    // ---- 9 independent wave reductions: se = sum e, acc[d] = sum e*dd ----
    float se = 0.f;
    #pragma unroll
    for (int c = 0; c < 2; ++c)
        #pragma unroll
        for (int j = 0; j < 4; ++j) se += e[c][j];

    float acc[8];
    #pragma unroll
    for (int d = 0; d < 8; ++d) {
        float a = 0.f;
        #pragma unroll
        for (int c = 0; c < 2; ++c)
            #pragma unroll
            for (int j = 0; j < 4; ++j) a = fmaf(e[c][j], dd[c][j][d], a);
        acc[d] = a;
    }
    #pragma unroll
    for (int o = 32; o > 0; o >>= 1) {
        se += __shfl_xor(se, o, 64);
        #pragma unroll
        for (int d = 0; d < 8; ++d) acc[d] += __shfl_xor(acc[d], o, 64);
    }
    const float sinv = __builtin_amdgcn_rcpf(se);

    // ---- W stores first (start HBM early): contiguous 1KB per instruction ----
    float w[2][4];
    #pragma unroll
    for (int c = 0; c < 2; ++c)
        #pragma unroll
        for (int j = 0; j < 4; ++j) w[c][j] = e[c][j] * sinv;
    {
        float* p = out + (size_t)b * M_N;
        #pragma unroll
        for (int c = 0; c < 2; ++c) {
            f32x4 wv = {w[c][0], w[c][1], w[c][2], w[c][3]};
            __builtin_nontemporal_store(wv, (f32x4*)(p + c * 256 + lane * 4));
        }
    }

    // ---- deriv = w*(mean - dd), mean[d] = acc[d]*sinv ----
    float meanv[8];
    #pragma unroll
    for (int d = 0; d < 8; ++d) meanv[d] = acc[d] * sinv;

    float* outD = out + (size_t)B_N * M_N + (size_t)b * (D_N * M_N);
    #pragma unroll
    for (int d = 0; d < 8; ++d) {
        #pragma unroll
        for (int c = 0; c < 2; ++c) {
            f32x4 v = {w[c][0] * (meanv[d] - dd[c][0][d]),
                       w[c][1] * (meanv[d] - dd[c][1][d]),
                       w[c][2] * (meanv[d] - dd[c][2][d]),
                       w[c][3] * (meanv[d] - dd[c][3][d])};
            __builtin_nontemporal_store(v, (f32x4*)(outD + d * M_N + c * 256 + lane * 4));
        }
    }
}

extern "C" void kernel_launch(void* const* d_in, const int* in_sizes, int n_in,
                              void* d_out, int out_size, void* d_ws, size_t ws_size,
                              hipStream_t stream) {
    const float* x = (const float*)d_in[0];
    const float* z = (const float*)d_in[1];
    const float* T = (const float*)d_in[2];
    float* out = (float*)d_out;

    dim3 grid(B_N / 8);   // 8 waves per block, 1 batch row per wave
    dim3 block(512);
    dsoftki_kernel<<<grid, block, 0, stream>>>(x, z, T, out);
}